// Round 7
// baseline (1133.519 us; speedup 1.0000x reference)
//
#include <hip/hip_runtime.h>
#include <hip/hip_bf16.h>

using bf16 = __hip_bfloat16;
typedef short short8 __attribute__((ext_vector_type(8)));
typedef float float4v __attribute__((ext_vector_type(4)));

__device__ __forceinline__ float b2f(unsigned short u){
  unsigned int x = ((unsigned int)u) << 16; float f;
  __builtin_memcpy(&f, &x, 4); return f;
}
__device__ __forceinline__ float b2f(bf16 v){ return __bfloat162float(v); }
__device__ __forceinline__ unsigned short f2bu(float x){
  bf16 h = __float2bfloat16(x); unsigned short u;
  __builtin_memcpy(&u, &h, 2); return u;
}

template<int MT>
__device__ __forceinline__ void ldvec(const float* p, float* d){
  #pragma unroll
  for (int i=0;i<MT;i+=4){
    float4 q = *reinterpret_cast<const float4*>(p+i);
    d[i]=q.x; d[i+1]=q.y; d[i+2]=q.z; d[i+3]=q.w;
  }
}

// ---------------- small VALU GEMM (only for W_eff = ow @ vw, 1 GF) ----------------------
template<int MT>
__launch_bounds__(256)
__global__ void gemm_k(const float* __restrict__ A, const float* __restrict__ B,
                       bf16* __restrict__ Cb, int M, int N, int K){
  constexpr int BM = 16*MT, BN = 16*MT, BK = 16;
  __shared__ float As[BK][BM+4];
  __shared__ float Bs[BK][BN+4];
  const int tid = threadIdx.x;
  const int tx = tid & 15, ty = tid >> 4;
  const int m0 = blockIdx.y*BM, n0 = blockIdx.x*BN;
  float acc[MT][MT] = {};
  constexpr int TPRA = 16/MT;
  const int ar = tid / TPRA;
  const int ak = (tid % TPRA)*MT;
  const int bk = tid >> 4;
  const int bn = (tid & 15)*MT;
  for (int k0 = 0; k0 < K; k0 += BK){
    float av[MT], bv[MT];
    ldvec<MT>(A + (size_t)(m0+ar)*K + k0 + ak, av);
    ldvec<MT>(B + (size_t)(k0+bk)*N + n0 + bn, bv);
    __syncthreads();
    #pragma unroll
    for (int j=0;j<MT;j++) As[ak+j][ar] = av[j];
    #pragma unroll
    for (int j=0;j<MT;j++) Bs[bk][bn+j] = bv[j];
    __syncthreads();
    #pragma unroll
    for (int kk=0;kk<BK;kk++){
      float a[MT], b[MT];
      #pragma unroll
      for (int i=0;i<MT;i++) a[i] = As[kk][ty*MT+i];
      #pragma unroll
      for (int j=0;j<MT;j++) b[j] = Bs[kk][tx*MT+j];
      #pragma unroll
      for (int i=0;i<MT;i++)
        #pragma unroll
        for (int j=0;j<MT;j++) acc[i][j] += a[i]*b[j];
    }
  }
  #pragma unroll
  for (int i=0;i<MT;i++){
    int m = m0 + ty*MT + i;
    #pragma unroll
    for (int j=0;j<MT;j++){
      int n = n0 + tx*MT + j;
      Cb[(size_t)m*N + n] = __float2bfloat16(acc[i][j]);
    }
  }
}

// -------- batched permuted transpose fp32->bf16: per z, in[R][Cc] -> out[(q%D)*G+q/D][R] -
template<class TO>
__launch_bounds__(256)
__global__ void permT_k(const float* __restrict__ inp, TO* __restrict__ outp,
                        int Cc, int R, int D, int G, long inS, long outS){
  __shared__ float t[64][65];
  int z = blockIdx.z;
  const float* in = inp + (size_t)z*inS;
  TO* out = outp + (size_t)z*outS;
  int c0 = blockIdx.x*64, r0 = blockIdx.y*64;
  int tid = threadIdx.x;
  int rr = tid>>2, c4 = (tid&3)*16;
  const float* p = in + (size_t)(r0+rr)*Cc + c0 + c4;
  #pragma unroll
  for (int j=0;j<16;j+=4){
    float4 q = *reinterpret_cast<const float4*>(p+j);
    t[rr][c4+j]=q.x; t[rr][c4+j+1]=q.y; t[rr][c4+j+2]=q.z; t[rr][c4+j+3]=q.w;
  }
  __syncthreads();
  int ql = tid>>2;
  int q = c0 + ql;
  int orow = (q % D)*G + q / D;
  TO* op = out + (size_t)orow*R + r0 + c4;
  #pragma unroll
  for (int j=0;j<16;j++){
    if constexpr (sizeof(TO)==2) op[j] = __float2bfloat16(t[c4+j][ql]);
    else op[j] = t[c4+j][ql];
  }
}

// -------- 3-block split transpose: rows of length 3R.
// PAT=0 (A-side): blocks (hi, lo, hi).  PAT=1 (B-side): blocks (hi, hi, lo).
// Paired dot over 3R gives ah*bh + al*bh + ah*bl  == fp32-accurate product.
template<int PAT>
__launch_bounds__(256)
__global__ void permTsplit3_k(const float* __restrict__ inp, unsigned short* __restrict__ outp,
                              int Cc, int R, int D, int G, long inS, long outS){
  __shared__ float t[64][65];
  int z = blockIdx.z;
  const float* in = inp + (size_t)z*inS;
  unsigned short* out = outp + (size_t)z*outS;
  int c0 = blockIdx.x*64, r0 = blockIdx.y*64;
  int tid = threadIdx.x;
  int rr = tid>>2, c4 = (tid&3)*16;
  const float* p = in + (size_t)(r0+rr)*Cc + c0 + c4;
  #pragma unroll
  for (int j=0;j<16;j+=4){
    float4 q = *reinterpret_cast<const float4*>(p+j);
    t[rr][c4+j]=q.x; t[rr][c4+j+1]=q.y; t[rr][c4+j+2]=q.z; t[rr][c4+j+3]=q.w;
  }
  __syncthreads();
  int ql = tid>>2;
  int q = c0 + ql;
  int orow = (q % D)*G + q / D;
  unsigned short* op = out + (size_t)orow*(3*R);
  #pragma unroll
  for (int j=0;j<16;j++){
    float v = t[c4+j][ql];
    unsigned short h = f2bu(v);
    unsigned short l = f2bu(v - b2f(h));
    int idx = r0 + c4 + j;
    if constexpr (PAT==0){
      op[idx] = h; op[R+idx] = l; op[2*R+idx] = h;
    } else {
      op[idx] = h; op[R+idx] = h; op[2*R+idx] = l;
    }
  }
}

// ================= unified direct-global MFMA GEMM =======================================
// C[m][f] = sum_k A[m][k]*B[f][k], bf16 operands, fragments loaded straight from L2.
// MODE 0: nonlocal  (epilogue: relu(acc+bias)+residual -> fp32 [m][1024])
// MODE 1: conv3d    (A rows via im2col map, B=wtt, K-split z=(kt,kh) -> part9)
// MODE 2: up1       (epilogue: relu+bias, convT scatter 8x8->16x16, write 3-block h/l/h)
// MODE 3: up2       (epilogue: bias, convT scatter 16x16->32x32, write fp32)
template<int MTM, int MTN, int MODE>
__launch_bounds__(256)
__global__ void mm_k(const unsigned short* __restrict__ A,
                     const unsigned short* __restrict__ B,
                     const float* __restrict__ bias,
                     const unsigned short* __restrict__ res,
                     float* __restrict__ outf,
                     unsigned short* __restrict__ outs,
                     int K){
  const int tid = threadIdx.x;
  const int wv = tid>>6, lane = tid&63, l15 = lane&15, quad = lane>>4;
  const int m0 = blockIdx.x*(MTM*16);
  const int fb = blockIdx.y*128 + wv*32;
  const int z = blockIdx.z;
  size_t aoff[MTM]; size_t boff[MTN];
  int kt=0, kh=0;
  if constexpr (MODE==1){ kt = z/3; kh = z%3; }
  #pragma unroll
  for (int mt=0; mt<MTM; ++mt){
    int m = m0 + mt*16 + l15;
    if constexpr (MODE==1){
      int b = m/392, r = m%392;
      int t = r/196, r2 = r%196;
      int hh = r2/14, ww = r2%14;
      int sp = ((b*4 + t + kt)*16 + hh + kh)*16 + ww;
      aoff[mt] = (size_t)sp*1024 + quad*8;
    } else {
      aoff[mt] = (size_t)m*K + quad*8;
    }
  }
  #pragma unroll
  for (int nt=0; nt<MTN; ++nt){
    int f = fb + nt*16 + l15;
    if constexpr (MODE==0)      boff[nt] = (size_t)f*1024 + quad*8;
    else if constexpr (MODE==1) boff[nt] = (size_t)f*27648 + (size_t)z*3072 + quad*8;
    else                        boff[nt] = ((size_t)z*512 + f)*(size_t)K + quad*8;
  }
  float4v acc[MTM][MTN];
  #pragma unroll
  for (int i=0;i<MTM;i++)
    #pragma unroll
    for (int j=0;j<MTN;j++) acc[i][j] = (float4v){0.f,0.f,0.f,0.f};

  short8 af[2][MTM]; short8 bf[2][MTN];
  #pragma unroll
  for (int mt=0;mt<MTM;++mt) af[0][mt] = *reinterpret_cast<const short8*>(A + aoff[mt]);
  #pragma unroll
  for (int nt=0;nt<MTN;++nt) bf[0][nt] = *reinterpret_cast<const short8*>(B + boff[nt]);

  for (int k0=0; k0<K; k0+=64){
    #pragma unroll
    for (int mt=0;mt<MTM;++mt)
      af[1][mt] = *reinterpret_cast<const short8*>(A + aoff[mt] + k0 + 32);
    #pragma unroll
    for (int nt=0;nt<MTN;++nt)
      bf[1][nt] = *reinterpret_cast<const short8*>(B + boff[nt] + k0 + 32);
    #pragma unroll
    for (int mt=0;mt<MTM;++mt)
      #pragma unroll
      for (int nt=0;nt<MTN;++nt)
        acc[mt][nt] = __builtin_amdgcn_mfma_f32_16x16x32_bf16(af[0][mt], bf[0][nt], acc[mt][nt],0,0,0);
    if (k0+64 < K){
      #pragma unroll
      for (int mt=0;mt<MTM;++mt)
        af[0][mt] = *reinterpret_cast<const short8*>(A + aoff[mt] + k0 + 64);
      #pragma unroll
      for (int nt=0;nt<MTN;++nt)
        bf[0][nt] = *reinterpret_cast<const short8*>(B + boff[nt] + k0 + 64);
    }
    #pragma unroll
    for (int mt=0;mt<MTM;++mt)
      #pragma unroll
      for (int nt=0;nt<MTN;++nt)
        acc[mt][nt] = __builtin_amdgcn_mfma_f32_16x16x32_bf16(af[1][mt], bf[1][nt], acc[mt][nt],0,0,0);
  }

  if constexpr (MODE==0){
    #pragma unroll
    for (int mt=0;mt<MTM;++mt)
      #pragma unroll
      for (int nt=0;nt<MTN;++nt){
        int f = fb + nt*16 + l15;
        float bi = bias[f];
        #pragma unroll
        for (int r=0;r<4;++r){
          int m = m0 + mt*16 + quad*4 + r;
          outf[(size_t)m*1024 + f] =
            fmaxf(acc[mt][nt][r]+bi, 0.f) + b2f(res[(size_t)m*1024 + f]);
        }
      }
  } else if constexpr (MODE==1){
    #pragma unroll
    for (int mt=0;mt<MTM;++mt)
      #pragma unroll
      for (int nt=0;nt<MTN;++nt){
        int f = fb + nt*16 + l15;
        #pragma unroll
        for (int r=0;r<4;++r){
          int m = m0 + mt*16 + quad*4 + r;
          outf[((size_t)z*1568 + m)*512 + f] = acc[mt][nt][r];
        }
      }
  } else if constexpr (MODE==2){
    int kk = z>>1, ll = z&1;
    #pragma unroll
    for (int mt=0;mt<MTM;++mt)
      #pragma unroll
      for (int nt=0;nt<MTN;++nt){
        int f = fb + nt*16 + l15;
        float bi = bias[f];
        #pragma unroll
        for (int r=0;r<4;++r){
          int m = m0 + mt*16 + quad*4 + r;
          int bt = m>>6, p = m&63;
          long orow = (long)bt*256 + (2*(p>>3)+kk)*16 + 2*(p&7)+ll;
          float v = fmaxf(acc[mt][nt][r]+bi, 0.f);
          unsigned short h = f2bu(v);
          unsigned short l = f2bu(v - b2f(h));
          unsigned short* rp = outs + (size_t)orow*1536 + f;
          rp[0] = h; rp[512] = l; rp[1024] = h;
        }
      }
  } else {
    int kk = z>>1, ll = z&1;
    #pragma unroll
    for (int mt=0;mt<MTM;++mt)
      #pragma unroll
      for (int nt=0;nt<MTN;++nt){
        int f = fb + nt*16 + l15;
        float bi = bias[f];
        #pragma unroll
        for (int r=0;r<4;++r){
          int m = m0 + mt*16 + quad*4 + r;
          int bt = m>>8, p = m&255;
          long orow = (long)bt*1024 + (2*(p>>4)+kk)*32 + 2*(p&15)+ll;
          outf[(size_t)orow*512 + f] = acc[mt][nt][r] + bi;
        }
      }
  }
}

// ---------------- BN column stats: part[slice][2][1024] ---------------------------------
__launch_bounds__(256)
__global__ void stats2_k(const float* __restrict__ y, float* __restrict__ part){
  int cb = blockIdx.x;   // 8 x 128 c
  int sl = blockIdx.y;   // 16 x 256 rows
  int tid = threadIdx.x;
  int c = cb*128 + (tid & 127);
  int h = tid >> 7;
  float s=0.f, s2=0.f;
  for (int i=0;i<128;i++){
    int r = sl*256 + h*128 + i;
    float v = y[(size_t)r*1024 + c];
    s += v; s2 += v*v;
  }
  __shared__ float rA[256], rB[256];
  rA[tid]=s; rB[tid]=s2; __syncthreads();
  if (tid < 128){
    part[(size_t)sl*2048 + c] = rA[tid]+rA[tid+128];
    part[(size_t)sl*2048 + 1024 + c] = rB[tid]+rB[tid+128];
  }
}

__global__ void stats_comb(const float* __restrict__ part, const float* __restrict__ g,
                           const float* __restrict__ beta, float* __restrict__ mv){
  int c = blockIdx.x*256 + threadIdx.x;   // 1024
  float S=0.f, S2=0.f;
  #pragma unroll
  for (int s=0;s<16;s++){ S += part[(size_t)s*2048 + c]; S2 += part[(size_t)s*2048 + 1024 + c]; }
  float m = S * (1.f/4096.f);
  float var = S2 * (1.f/4096.f) - m*m;
  float inv = rsqrtf(var + 1e-5f);
  float sc = inv * g[c];
  mv[c] = sc;
  mv[1024 + c] = beta[c] - m*sc;
}

__global__ void norm2_k(const float* __restrict__ y, const float* __restrict__ mv,
                        unsigned short* __restrict__ xcl){
  int idx = blockIdx.x*256 + threadIdx.x;
  int c = idx & 1023;
  xcl[idx] = f2bu(y[idx]*mv[c] + mv[1024+c]);
}

// ---------------- weight permute: wtt[f][j*1024+c] = tp_w[f][c*27+j]  (fp32->bf16) ------
__launch_bounds__(256)
__global__ void wperm_k(const float* __restrict__ w, unsigned short* __restrict__ wtt){
  __shared__ float ls[3456];
  int f = blockIdx.x;
  const float* src = w + (size_t)f*27648;
  unsigned short* dst = wtt + (size_t)f*27648;
  for (int cc=0; cc<8; ++cc){
    __syncthreads();
    for (int i=threadIdx.x; i<3456; i+=256) ls[i] = src[cc*3456 + i];
    __syncthreads();
    for (int u=threadIdx.x; u<3456; u+=256){
      int j = u >> 7, c = u & 127;
      dst[(size_t)j*1024 + cc*128 + c] = f2bu(ls[c*27 + j]);
    }
  }
}

// ---------------- goal_pre = mean over 392 pos of relu(sum9 parts + bias) ---------------
__launch_bounds__(256)
__global__ void gp2_k(const float* __restrict__ part9, const float* __restrict__ tpb,
                      float* __restrict__ gp){
  int b = blockIdx.x;
  int fc = blockIdx.y;
  int fi = threadIdx.x & 31, pi = threadIdx.x >> 5;
  int f = fc*32 + fi;
  float bias = tpb[f];
  float a = 0.f;
  for (int p = pi; p < 392; p += 8){
    size_t base = ((size_t)(b*392 + p))*512 + f;
    float v = bias;
    #pragma unroll
    for (int i=0;i<9;i++) v += part9[(size_t)i*802816 + base];
    a += fmaxf(v, 0.f);
  }
  __shared__ float red[256];
  red[threadIdx.x] = a; __syncthreads();
  for (int st=4; st>0; st>>=1){
    if (pi < st) red[pi*32+fi] += red[(pi+st)*32+fi];
    __syncthreads();
  }
  if (pi==0) gp[b*512 + f] = red[fi] * (1.f/392.f);
}

// ---------------- PE table: peN[n][c] ---------------------------------------------------
__global__ void pen_k(float* __restrict__ peN){
  int idx = blockIdx.x*256 + threadIdx.x;   // 524288
  int n = idx >> 9, c = idx & 511;
  float div = expf(-0.035977892f * (float)(c>>1));   // 2*ln(10000)/512
  float ang = (float)n * div;
  peN[idx] = (c & 1) ? cosf(ang) : sinf(ang);
}

// ---------------- SG[bt][n] = dot(scl[bt*1024+n][:], gp[bt/6][:]) -----------------------
__launch_bounds__(256)
__global__ void sg2_k(const float* __restrict__ scl, const float* __restrict__ gp,
                      float* __restrict__ SG){
  int bt = blockIdx.x, nb = blockIdx.y;   // 24 x 16
  int tid = threadIdx.x;
  int wv = tid >> 6, lane = tid & 63;
  __shared__ float gs[512];
  gs[tid] = gp[(bt/6)*512 + tid];
  gs[tid+256] = gp[(bt/6)*512 + 256 + tid];
  __syncthreads();
  for (int i=0;i<16;i++){
    int n = nb*64 + wv*16 + i;
    const float* row = scl + ((size_t)bt*1024 + n)*512 + lane*8;
    float4 a = *reinterpret_cast<const float4*>(row);
    float4 b = *reinterpret_cast<const float4*>(row+4);
    const float* g = &gs[lane*8];
    float s = a.x*g[0] + a.y*g[1] + a.z*g[2] + a.w*g[3]
            + b.x*g[4] + b.y*g[5] + b.z*g[6] + b.w*g[7];
    #pragma unroll
    for (int off=32; off; off>>=1) s += __shfl_xor(s, off);
    if (lane==0) SG[bt*1024 + n] = s;
  }
}

// ---------------- softmax over n: attn[bt][n] normalized --------------------------------
__launch_bounds__(256)
__global__ void softmax_k(const float* __restrict__ SG, float* __restrict__ attn){
  int bt = blockIdx.x; int tid = threadIdx.x;
  float4 v = *reinterpret_cast<const float4*>(SG + bt*1024 + tid*4);
  float mx = fmaxf(fmaxf(v.x,v.y), fmaxf(v.z,v.w));
  __shared__ float red[256];
  red[tid] = mx; __syncthreads();
  for (int st=128; st>0; st>>=1){
    if (tid<st) red[tid] = fmaxf(red[tid], red[tid+st]);
    __syncthreads();
  }
  float m = red[0]; __syncthreads();
  float4 e;
  e.x = expf(v.x-m); e.y = expf(v.y-m); e.z = expf(v.z-m); e.w = expf(v.w-m);
  red[tid] = e.x+e.y+e.z+e.w; __syncthreads();
  for (int st=128; st>0; st>>=1){
    if (tid<st) red[tid] += red[tid+st];
    __syncthreads();
  }
  float inv = 1.0f/red[0];
  e.x*=inv; e.y*=inv; e.z*=inv; e.w*=inv;
  *reinterpret_cast<float4*>(attn + bt*1024 + tid*4) = e;
}

// ---------------- part_sga[bt][sl][c] = sum_{n in slice} attn[n]*(scl[n][c]+pe[n][c]) ---
__launch_bounds__(256)
__global__ void sga2_k(const float* __restrict__ scl, const float* __restrict__ peN,
                       const float* __restrict__ attn, float* __restrict__ part){
  int bt = blockIdx.x, sl = blockIdx.y;   // 24 x 8
  int tid = threadIdx.x;
  __shared__ float at[128];
  if (tid < 128) at[tid] = attn[bt*1024 + sl*128 + tid];
  __syncthreads();
  float acc0 = 0.f, acc1 = 0.f;
  for (int j=0;j<128;j++){
    int n = sl*128 + j;
    float a = at[j];
    const float* row = scl + ((size_t)bt*1024 + n)*512;
    const float* pe  = peN + (size_t)n*512;
    acc0 += a * (row[tid] + pe[tid]);
    acc1 += a * (row[tid+256] + pe[tid+256]);
  }
  part[((size_t)bt*8 + sl)*512 + tid] = acc0;
  part[((size_t)bt*8 + sl)*512 + tid + 256] = acc1;
}

__global__ void sga_red(const float* __restrict__ part, float* __restrict__ sga){
  int bt = blockIdx.x; int tid = threadIdx.x;
  #pragma unroll
  for (int h=0; h<2; ++h){
    int c = tid + h*256;
    float s = 0.f;
    #pragma unroll
    for (int sl=0; sl<8; ++sl) s += part[((size_t)bt*8 + sl)*512 + c];
    sga[(size_t)bt*512 + c] = s;
  }
}

// ---------------- 512->512(relu)->128 MLP head (fp32 weights) ---------------------------
__launch_bounds__(256)
__global__ void mlp_k(const float* __restrict__ in, const float* __restrict__ w1,
                      const float* __restrict__ b1, const float* __restrict__ w2,
                      const float* __restrict__ b2, float* __restrict__ out){
  int bb = blockIdx.x; int tid = threadIdx.x;
  __shared__ float xv[512]; __shared__ float h[512];
  xv[tid] = in[(size_t)bb*512 + tid];
  xv[tid+256] = in[(size_t)bb*512 + 256 + tid];
  __syncthreads();
  #pragma unroll
  for (int oo=0;oo<2;oo++){
    int o = tid + oo*256;
    const float* wr = w1 + (size_t)o*512;
    float a=0.f;
    for (int c=0;c<512;c+=4){
      float4 q = *reinterpret_cast<const float4*>(wr+c);
      a += xv[c]*q.x + xv[c+1]*q.y + xv[c+2]*q.z + xv[c+3]*q.w;
    }
    h[o] = fmaxf(a + b1[o], 0.f);
  }
  __syncthreads();
  if (tid < 128){
    const float* wr = w2 + (size_t)tid*512;
    float a=0.f;
    for (int c=0;c<512;c+=4){
      float4 q = *reinterpret_cast<const float4*>(wr+c);
      a += h[c]*q.x + h[c+1]*q.y + h[c+2]*q.z + h[c+3]*q.w;
    }
    out[(size_t)bb*128+tid] = a + b2[tid];
  }
}

extern "C" void kernel_launch(void* const* d_in, const int* in_sizes, int n_in,
                              void* d_out, int out_size, void* d_ws, size_t ws_size,
                              hipStream_t stream){
  (void)in_sizes; (void)n_in; (void)out_size; (void)ws_size;
  const float* ctx   = (const float*)d_in[0];
  const float* frame = (const float*)d_in[1];
  const float* nl_vw[2] = {(const float*)d_in[4],  (const float*)d_in[11]};
  const float* nl_ow[2] = {(const float*)d_in[5],  (const float*)d_in[12]};
  const float* nl_ob[2] = {(const float*)d_in[6],  (const float*)d_in[13]};
  const float* nl_g[2]  = {(const float*)d_in[7],  (const float*)d_in[14]};
  const float* nl_be[2] = {(const float*)d_in[8],  (const float*)d_in[15]};
  const float* tp_w = (const float*)d_in[16]; const float* tp_b = (const float*)d_in[17];
  const float* up1w = (const float*)d_in[18]; const float* up1b = (const float*)d_in[19];
  const float* up2w = (const float*)d_in[20]; const float* up2b = (const float*)d_in[21];
  const float* og1w = (const float*)d_in[22]; const float* og1b = (const float*)d_in[23];
  const float* og2w = (const float*)d_in[24]; const float* og2b = (const float*)d_in[25];
  const float* os1w = (const float*)d_in[26]; const float* os1b = (const float*)d_in[27];
  const float* os2w = (const float*)d_in[28]; const float* os2b = (const float*)d_in[29];
  float* out = (float*)d_out;

  char* wsp = (char*)d_ws;
  // ---- persistent region (~23.9 MB) ----
  float* part_bn = (float*)(wsp);                 // 131072  [16][2048]
  float* mv      = (float*)(wsp + 131072);        // 8192
  float* gp      = (float*)(wsp + 139264);        // 8192
  float* SG      = (float*)(wsp + 147456);        // 98304
  float* attn    = (float*)(wsp + 245760);        // 98304
  float* sga     = (float*)(wsp + 344064);        // 49152
  float* psga    = (float*)(wsp + 393216);        // 393216 [24][8][512]
  float* peN     = (float*)(wsp + 786432);        // 2097152 [1024][512]
  bf16*  weff    = (bf16*) (wsp + 2883584);       // 2097152 [1024][1024] bf16
  unsigned short* w1sp = (unsigned short*)(wsp + 4980736);   // 12582912 [4][512][3072]
  unsigned short* w2sp = (unsigned short*)(wsp + 17563648);  // 6291456  [4][512][1536]
  char* ov = wsp + 23855104;
  // phase 1 (nonlocal):
  bf16*  xcl  = (bf16*) (ov);                     // 8 MB [4096][1024]
  float* ybuf = (float*)(ov + 8388608);           // 16 MB [4096][1024]
  // phase 2 (conv): wtt aliases ybuf (written after last norm2)
  unsigned short* wtt = (unsigned short*)(ov + 8388608);   // 28.3 MB [512][27648]
  float* part9 = (float*)(ov + 36700160);         // 28.9 MB [9][1568][512]
  // frame staging: aliases part9 (written after gp2_k reads part9)
  unsigned short* Fsp = (unsigned short*)(ov + 36700160);  // 9.4 MB [1536][3072]
  // phase 3 (after gp2_k; xcl/wtt dead):
  unsigned short* s1sp = (unsigned short*)(ov);   // 18.9 MB [6144][1536]
  float* scl  = (float*)(ov + 18874368);          // 50.3 MB [24576][512]

  // prep (independent)
  permT_k<bf16><<<dim3(4,16,16),256,0,stream>>>(ctx, xcl, 256, 1024, 1, 1, 262144L, 262144L);
  permTsplit3_k<1><<<dim3(32,16,1),256,0,stream>>>(up1w, w1sp, 2048, 1024, 4, 512, 0L, 0L);
  permTsplit3_k<1><<<dim3(32,8,1),256,0,stream>>>(up2w, w2sp, 2048, 512, 4, 512, 0L, 0L);
  pen_k<<<2048,256,0,stream>>>(peN);

  // nonlocal layers
  for (int l=0;l<2;l++){
    gemm_k<4><<<dim3(16,16),256,0,stream>>>(nl_ow[l], nl_vw[l], weff, 1024,1024,512);
    mm_k<4,2,0><<<dim3(64,8,1),256,0,stream>>>((const unsigned short*)xcl,
        (const unsigned short*)weff, nl_ob[l], (const unsigned short*)xcl,
        ybuf, nullptr, 1024);
    stats2_k<<<dim3(8,16),256,0,stream>>>(ybuf, part_bn);
    stats_comb<<<4,256,0,stream>>>(part_bn, nl_g[l], nl_be[l], mv);
    norm2_k<<<16384,256,0,stream>>>(ybuf, mv, (unsigned short*)xcl);
  }

  // temporal-pool conv
  wperm_k<<<512,256,0,stream>>>(tp_w, wtt);
  mm_k<7,2,1><<<dim3(14,4,9),256,0,stream>>>((const unsigned short*)xcl, wtt,
      nullptr, nullptr, part9, nullptr, 3072);
  gp2_k<<<dim3(4,16),256,0,stream>>>(part9, tp_b, gp);

  // frame path (3-block split-bf16 == fp32-accurate); Fsp aliases part9 -> after gp2_k
  permTsplit3_k<0><<<dim3(1,16,24),256,0,stream>>>(frame, Fsp, 64, 1024, 1, 1, 65536L, 196608L);
  mm_k<4,2,2><<<dim3(24,4,4),256,0,stream>>>(Fsp, w1sp, up1b, nullptr,
      nullptr, s1sp, 3072);
  mm_k<8,2,3><<<dim3(48,4,4),256,0,stream>>>(s1sp, w2sp, up2b, nullptr,
      scl, nullptr, 1536);

  // attention tail
  sg2_k<<<dim3(24,16),256,0,stream>>>(scl, gp, SG);
  softmax_k<<<24,256,0,stream>>>(SG, attn);
  sga2_k<<<dim3(24,8),256,0,stream>>>(scl, peN, attn, psga);
  sga_red<<<24,256,0,stream>>>(psga, sga);

  // heads
  mlp_k<<<4,256,0,stream>>>(gp, og1w, og1b, og2w, og2b, out);
  mlp_k<<<24,256,0,stream>>>(sga, os1w, os1b, os2w, os2b, out + 512);
}

// Round 8
// 802.415 us; speedup vs baseline: 1.4126x; 1.4126x over previous
//
#include <hip/hip_runtime.h>
#include <hip/hip_bf16.h>

using bf16 = __hip_bfloat16;
typedef short short8 __attribute__((ext_vector_type(8)));
typedef float float4v __attribute__((ext_vector_type(4)));

__device__ __forceinline__ float b2f(unsigned short u){
  unsigned int x = ((unsigned int)u) << 16; float f;
  __builtin_memcpy(&f, &x, 4); return f;
}
__device__ __forceinline__ float b2f(bf16 v){ return __bfloat162float(v); }
__device__ __forceinline__ unsigned short f2bu(float x){
  bf16 h = __float2bfloat16(x); unsigned short u;
  __builtin_memcpy(&u, &h, 2); return u;
}

template<int MT>
__device__ __forceinline__ void ldvec(const float* p, float* d){
  #pragma unroll
  for (int i=0;i<MT;i+=4){
    float4 q = *reinterpret_cast<const float4*>(p+i);
    d[i]=q.x; d[i+1]=q.y; d[i+2]=q.z; d[i+3]=q.w;
  }
}

// ---------------- small VALU GEMM (only for W_eff = ow @ vw, 1 GF) ----------------------
template<int MT>
__launch_bounds__(256)
__global__ void gemm_k(const float* __restrict__ A, const float* __restrict__ B,
                       bf16* __restrict__ Cb, int M, int N, int K){
  constexpr int BM = 16*MT, BN = 16*MT, BK = 16;
  __shared__ float As[BK][BM+4];
  __shared__ float Bs[BK][BN+4];
  const int tid = threadIdx.x;
  const int tx = tid & 15, ty = tid >> 4;
  const int m0 = blockIdx.y*BM, n0 = blockIdx.x*BN;
  float acc[MT][MT] = {};
  constexpr int TPRA = 16/MT;
  const int ar = tid / TPRA;
  const int ak = (tid % TPRA)*MT;
  const int bk = tid >> 4;
  const int bn = (tid & 15)*MT;
  for (int k0 = 0; k0 < K; k0 += BK){
    float av[MT], bv[MT];
    ldvec<MT>(A + (size_t)(m0+ar)*K + k0 + ak, av);
    ldvec<MT>(B + (size_t)(k0+bk)*N + n0 + bn, bv);
    __syncthreads();
    #pragma unroll
    for (int j=0;j<MT;j++) As[ak+j][ar] = av[j];
    #pragma unroll
    for (int j=0;j<MT;j++) Bs[bk][bn+j] = bv[j];
    __syncthreads();
    #pragma unroll
    for (int kk=0;kk<BK;kk++){
      float a[MT], b[MT];
      #pragma unroll
      for (int i=0;i<MT;i++) a[i] = As[kk][ty*MT+i];
      #pragma unroll
      for (int j=0;j<MT;j++) b[j] = Bs[kk][tx*MT+j];
      #pragma unroll
      for (int i=0;i<MT;i++)
        #pragma unroll
        for (int j=0;j<MT;j++) acc[i][j] += a[i]*b[j];
    }
  }
  #pragma unroll
  for (int i=0;i<MT;i++){
    int m = m0 + ty*MT + i;
    #pragma unroll
    for (int j=0;j<MT;j++){
      int n = n0 + tx*MT + j;
      Cb[(size_t)m*N + n] = __float2bfloat16(acc[i][j]);
    }
  }
}

// -------- batched permuted transpose fp32->bf16: per z, in[R][Cc] -> out[(q%D)*G+q/D][R] -
template<class TO>
__launch_bounds__(256)
__global__ void permT_k(const float* __restrict__ inp, TO* __restrict__ outp,
                        int Cc, int R, int D, int G, long inS, long outS){
  __shared__ float t[64][65];
  int z = blockIdx.z;
  const float* in = inp + (size_t)z*inS;
  TO* out = outp + (size_t)z*outS;
  int c0 = blockIdx.x*64, r0 = blockIdx.y*64;
  int tid = threadIdx.x;
  int rr = tid>>2, c4 = (tid&3)*16;
  const float* p = in + (size_t)(r0+rr)*Cc + c0 + c4;
  #pragma unroll
  for (int j=0;j<16;j+=4){
    float4 q = *reinterpret_cast<const float4*>(p+j);
    t[rr][c4+j]=q.x; t[rr][c4+j+1]=q.y; t[rr][c4+j+2]=q.z; t[rr][c4+j+3]=q.w;
  }
  __syncthreads();
  int ql = tid>>2;
  int q = c0 + ql;
  int orow = (q % D)*G + q / D;
  TO* op = out + (size_t)orow*R + r0 + c4;
  #pragma unroll
  for (int j=0;j<16;j++){
    if constexpr (sizeof(TO)==2) op[j] = __float2bfloat16(t[c4+j][ql]);
    else op[j] = t[c4+j][ql];
  }
}

// -------- 3-block split transpose: rows of length 3R.
// PAT=0 (A-side): blocks (hi, lo, hi).  PAT=1 (B-side): blocks (hi, hi, lo).
// Paired dot over 3R gives ah*bh + al*bh + ah*bl  == fp32-accurate product.
template<int PAT>
__launch_bounds__(256)
__global__ void permTsplit3_k(const float* __restrict__ inp, unsigned short* __restrict__ outp,
                              int Cc, int R, int D, int G, long inS, long outS){
  __shared__ float t[64][65];
  int z = blockIdx.z;
  const float* in = inp + (size_t)z*inS;
  unsigned short* out = outp + (size_t)z*outS;
  int c0 = blockIdx.x*64, r0 = blockIdx.y*64;
  int tid = threadIdx.x;
  int rr = tid>>2, c4 = (tid&3)*16;
  const float* p = in + (size_t)(r0+rr)*Cc + c0 + c4;
  #pragma unroll
  for (int j=0;j<16;j+=4){
    float4 q = *reinterpret_cast<const float4*>(p+j);
    t[rr][c4+j]=q.x; t[rr][c4+j+1]=q.y; t[rr][c4+j+2]=q.z; t[rr][c4+j+3]=q.w;
  }
  __syncthreads();
  int ql = tid>>2;
  int q = c0 + ql;
  int orow = (q % D)*G + q / D;
  unsigned short* op = out + (size_t)orow*(3*R);
  #pragma unroll
  for (int j=0;j<16;j++){
    float v = t[c4+j][ql];
    unsigned short h = f2bu(v);
    unsigned short l = f2bu(v - b2f(h));
    int idx = r0 + c4 + j;
    if constexpr (PAT==0){
      op[idx] = h; op[R+idx] = l; op[2*R+idx] = h;
    } else {
      op[idx] = h; op[R+idx] = h; op[2*R+idx] = l;
    }
  }
}

// ================= unified LDS-staged MFMA GEMM with register prefetch ===================
// C[m][f] = sum_k A[m][k]*B[f][k], bf16, BK=32, f-tile 128 (4 waves x 2 n-frags).
// LDS layout: 16B chunk c of row r stored at slot r*4 + (c ^ ((r>>1)&3))  -> staging stays
// 64B-coalesced per row; fragment ds_read_b128 hits <=2-way banks (free).
// MODE 0: nonlocal (relu(acc+bias)+residual -> fp32), 1: conv3d im2col K-split z,
// MODE 2: up1 (relu+bias, convT scatter 8x8->16x16, 3-block h/l/h out), 3: up2 (bias, scatter, fp32)
template<int MTM, int MODE>
__launch_bounds__(256)
__global__ void mmL_k(const unsigned short* __restrict__ A,
                      const unsigned short* __restrict__ B,
                      const float* __restrict__ bias,
                      const unsigned short* __restrict__ res,
                      float* __restrict__ outf,
                      unsigned short* __restrict__ outs,
                      int K){
  constexpr int AR = MTM*16;
  constexpr int ASLOT = AR*4;          // 16B slots in A tile
  __shared__ __align__(16) short As[AR*32];
  __shared__ __align__(16) short Bs[128*32];
  const int tid = threadIdx.x;
  const int wv = tid>>6, lane = tid&63, l15 = lane&15, quad = lane>>4;
  const int m0 = blockIdx.x*AR;
  const int fblk = blockIdx.y*128;
  const int z = blockIdx.z;

  // ---- staging addresses ----
  size_t aAddr = 0;
  {
    int arow = tid>>2, acs = tid&3;
    int ac = acs ^ ((arow>>1)&3);
    if (tid < ASLOT){
      int m = m0 + arow;
      if constexpr (MODE==1){
        int mm = m < 1568 ? m : 1567;
        int b = mm/392, r = mm%392;
        int t = r/196, r2 = r%196;
        int hh = r2/14, ww = r2%14;
        int kt = z/3, kh = z%3;
        int sp = ((b*4 + t + kt)*16 + hh + kh)*16 + ww;
        aAddr = (size_t)sp*1024 + ac*8;
      } else {
        aAddr = (size_t)m*K + ac*8;
      }
    }
  }
  size_t bAddr[2];
  #pragma unroll
  for (int it=0; it<2; ++it){
    int s = tid + it*256;
    int row = s>>2, cs = s&3;
    int c = cs ^ ((row>>1)&3);
    int f = fblk + row;
    if constexpr (MODE==0)      bAddr[it] = (size_t)f*1024 + c*8;
    else if constexpr (MODE==1) bAddr[it] = (size_t)f*27648 + (size_t)z*3072 + c*8;
    else                        bAddr[it] = ((size_t)z*512 + f)*(size_t)K + c*8;
  }
  // ---- fragment LDS slots (swizzled) ----
  int aslot[MTM];
  #pragma unroll
  for (int mt=0;mt<MTM;++mt){
    int row = mt*16 + l15;
    aslot[mt] = row*4 + (quad ^ ((row>>1)&3));
  }
  int bslot[2];
  #pragma unroll
  for (int nt=0;nt<2;++nt){
    int row = wv*32 + nt*16 + l15;
    bslot[nt] = row*4 + (quad ^ ((row>>1)&3));
  }

  float4v acc[MTM][2];
  #pragma unroll
  for (int i=0;i<MTM;i++){ acc[i][0]=(float4v){0,0,0,0}; acc[i][1]=(float4v){0,0,0,0}; }

  uint4 pa = {}, pb0, pb1;
  if (tid < ASLOT) pa = *reinterpret_cast<const uint4*>(A + aAddr);
  pb0 = *reinterpret_cast<const uint4*>(B + bAddr[0]);
  pb1 = *reinterpret_cast<const uint4*>(B + bAddr[1]);

  for (int k0=0; k0<K; k0+=32){
    __syncthreads();
    if (tid < ASLOT) *reinterpret_cast<uint4*>(As + tid*8) = pa;
    *reinterpret_cast<uint4*>(Bs + tid*8) = pb0;
    *reinterpret_cast<uint4*>(Bs + (tid+256)*8) = pb1;
    __syncthreads();
    if (k0+32 < K){
      if (tid < ASLOT) pa = *reinterpret_cast<const uint4*>(A + aAddr + k0 + 32);
      pb0 = *reinterpret_cast<const uint4*>(B + bAddr[0] + k0 + 32);
      pb1 = *reinterpret_cast<const uint4*>(B + bAddr[1] + k0 + 32);
    }
    short8 bf0 = *reinterpret_cast<const short8*>(Bs + bslot[0]*8);
    short8 bf1 = *reinterpret_cast<const short8*>(Bs + bslot[1]*8);
    #pragma unroll
    for (int mt=0;mt<MTM;++mt){
      short8 af = *reinterpret_cast<const short8*>(As + aslot[mt]*8);
      acc[mt][0] = __builtin_amdgcn_mfma_f32_16x16x32_bf16(af, bf0, acc[mt][0],0,0,0);
      acc[mt][1] = __builtin_amdgcn_mfma_f32_16x16x32_bf16(af, bf1, acc[mt][1],0,0,0);
    }
  }

  if constexpr (MODE==0){
    #pragma unroll
    for (int mt=0;mt<MTM;++mt)
      #pragma unroll
      for (int nt=0;nt<2;++nt){
        int f = fblk + wv*32 + nt*16 + l15;
        float bi = bias[f];
        #pragma unroll
        for (int r=0;r<4;++r){
          int m = m0 + mt*16 + quad*4 + r;
          outf[(size_t)m*1024 + f] =
            fmaxf(acc[mt][nt][r]+bi, 0.f) + b2f(res[(size_t)m*1024 + f]);
        }
      }
  } else if constexpr (MODE==1){
    #pragma unroll
    for (int mt=0;mt<MTM;++mt)
      #pragma unroll
      for (int nt=0;nt<2;++nt){
        int f = fblk + wv*32 + nt*16 + l15;
        #pragma unroll
        for (int r=0;r<4;++r){
          int m = m0 + mt*16 + quad*4 + r;
          if (m < 1568) outf[((size_t)z*1568 + m)*512 + f] = acc[mt][nt][r];
        }
      }
  } else if constexpr (MODE==2){
    int kk = z>>1, ll = z&1;
    #pragma unroll
    for (int mt=0;mt<MTM;++mt)
      #pragma unroll
      for (int nt=0;nt<2;++nt){
        int f = fblk + wv*32 + nt*16 + l15;
        float bi = bias[f];
        #pragma unroll
        for (int r=0;r<4;++r){
          int m = m0 + mt*16 + quad*4 + r;
          int bt = m>>6, p = m&63;
          long orow = (long)bt*256 + (2*(p>>3)+kk)*16 + 2*(p&7)+ll;
          float v = fmaxf(acc[mt][nt][r]+bi, 0.f);
          unsigned short h = f2bu(v);
          unsigned short l = f2bu(v - b2f(h));
          unsigned short* rp = outs + (size_t)orow*1536 + f;
          rp[0] = h; rp[512] = l; rp[1024] = h;
        }
      }
  } else {
    int kk = z>>1, ll = z&1;
    #pragma unroll
    for (int mt=0;mt<MTM;++mt)
      #pragma unroll
      for (int nt=0;nt<2;++nt){
        int f = fblk + wv*32 + nt*16 + l15;
        float bi = bias[f];
        #pragma unroll
        for (int r=0;r<4;++r){
          int m = m0 + mt*16 + quad*4 + r;
          int bt = m>>8, p = m&255;
          long orow = (long)bt*1024 + (2*(p>>4)+kk)*32 + 2*(p&15)+ll;
          outf[(size_t)orow*512 + f] = acc[mt][nt][r] + bi;
        }
      }
  }
}

// ---------------- BN column stats: part[slice][2][1024] ---------------------------------
__launch_bounds__(256)
__global__ void stats2_k(const float* __restrict__ y, float* __restrict__ part){
  int cb = blockIdx.x;   // 8 x 128 c
  int sl = blockIdx.y;   // 16 x 256 rows
  int tid = threadIdx.x;
  int c = cb*128 + (tid & 127);
  int h = tid >> 7;
  float s=0.f, s2=0.f;
  for (int i=0;i<128;i++){
    int r = sl*256 + h*128 + i;
    float v = y[(size_t)r*1024 + c];
    s += v; s2 += v*v;
  }
  __shared__ float rA[256], rB[256];
  rA[tid]=s; rB[tid]=s2; __syncthreads();
  if (tid < 128){
    part[(size_t)sl*2048 + c] = rA[tid]+rA[tid+128];
    part[(size_t)sl*2048 + 1024 + c] = rB[tid]+rB[tid+128];
  }
}

__global__ void stats_comb(const float* __restrict__ part, const float* __restrict__ g,
                           const float* __restrict__ beta, float* __restrict__ mv){
  int c = blockIdx.x*256 + threadIdx.x;   // 1024
  float S=0.f, S2=0.f;
  #pragma unroll
  for (int s=0;s<16;s++){ S += part[(size_t)s*2048 + c]; S2 += part[(size_t)s*2048 + 1024 + c]; }
  float m = S * (1.f/4096.f);
  float var = S2 * (1.f/4096.f) - m*m;
  float inv = rsqrtf(var + 1e-5f);
  float sc = inv * g[c];
  mv[c] = sc;
  mv[1024 + c] = beta[c] - m*sc;
}

__global__ void norm2_k(const float* __restrict__ y, const float* __restrict__ mv,
                        unsigned short* __restrict__ xcl){
  int idx = blockIdx.x*256 + threadIdx.x;
  int c = idx & 1023;
  xcl[idx] = f2bu(y[idx]*mv[c] + mv[1024+c]);
}

// ---------------- weight permute: wtt[f][j*1024+c] = tp_w[f][c*27+j]  (fp32->bf16) ------
__launch_bounds__(256)
__global__ void wperm_k(const float* __restrict__ w, unsigned short* __restrict__ wtt){
  __shared__ float ls[3456];
  int f = blockIdx.x;
  const float* src = w + (size_t)f*27648;
  unsigned short* dst = wtt + (size_t)f*27648;
  for (int cc=0; cc<8; ++cc){
    __syncthreads();
    for (int i=threadIdx.x; i<3456; i+=256) ls[i] = src[cc*3456 + i];
    __syncthreads();
    for (int u=threadIdx.x; u<3456; u+=256){
      int j = u >> 7, c = u & 127;
      dst[(size_t)j*1024 + cc*128 + c] = f2bu(ls[c*27 + j]);
    }
  }
}

// ---------------- goal_pre = mean over 392 pos of relu(sum9 parts + bias) ---------------
__launch_bounds__(256)
__global__ void gp2_k(const float* __restrict__ part9, const float* __restrict__ tpb,
                      float* __restrict__ gp){
  int b = blockIdx.x;
  int fc = blockIdx.y;
  int fi = threadIdx.x & 31, pi = threadIdx.x >> 5;
  int f = fc*32 + fi;
  float bias = tpb[f];
  float a = 0.f;
  for (int p = pi; p < 392; p += 8){
    size_t base = ((size_t)(b*392 + p))*512 + f;
    float v = bias;
    #pragma unroll
    for (int i=0;i<9;i++) v += part9[(size_t)i*802816 + base];
    a += fmaxf(v, 0.f);
  }
  __shared__ float red[256];
  red[threadIdx.x] = a; __syncthreads();
  for (int st=4; st>0; st>>=1){
    if (pi < st) red[pi*32+fi] += red[(pi+st)*32+fi];
    __syncthreads();
  }
  if (pi==0) gp[b*512 + f] = red[fi] * (1.f/392.f);
}

// ---------------- PE table: peN[n][c] ---------------------------------------------------
__global__ void pen_k(float* __restrict__ peN){
  int idx = blockIdx.x*256 + threadIdx.x;   // 524288
  int n = idx >> 9, c = idx & 511;
  float div = expf(-0.035977892f * (float)(c>>1));   // 2*ln(10000)/512
  float ang = (float)n * div;
  peN[idx] = (c & 1) ? cosf(ang) : sinf(ang);
}

// ---------------- SG[bt][n] = dot(scl[bt*1024+n][:], gp[bt/6][:]) -----------------------
__launch_bounds__(256)
__global__ void sg2_k(const float* __restrict__ scl, const float* __restrict__ gp,
                      float* __restrict__ SG){
  int bt = blockIdx.x, nb = blockIdx.y;   // 24 x 16
  int tid = threadIdx.x;
  int wv = tid >> 6, lane = tid & 63;
  __shared__ float gs[512];
  gs[tid] = gp[(bt/6)*512 + tid];
  gs[tid+256] = gp[(bt/6)*512 + 256 + tid];
  __syncthreads();
  for (int i=0;i<16;i++){
    int n = nb*64 + wv*16 + i;
    const float* row = scl + ((size_t)bt*1024 + n)*512 + lane*8;
    float4 a = *reinterpret_cast<const float4*>(row);
    float4 b = *reinterpret_cast<const float4*>(row+4);
    const float* g = &gs[lane*8];
    float s = a.x*g[0] + a.y*g[1] + a.z*g[2] + a.w*g[3]
            + b.x*g[4] + b.y*g[5] + b.z*g[6] + b.w*g[7];
    #pragma unroll
    for (int off=32; off; off>>=1) s += __shfl_xor(s, off);
    if (lane==0) SG[bt*1024 + n] = s;
  }
}

// ---------------- softmax over n: attn[bt][n] normalized --------------------------------
__launch_bounds__(256)
__global__ void softmax_k(const float* __restrict__ SG, float* __restrict__ attn){
  int bt = blockIdx.x; int tid = threadIdx.x;
  float4 v = *reinterpret_cast<const float4*>(SG + bt*1024 + tid*4);
  float mx = fmaxf(fmaxf(v.x,v.y), fmaxf(v.z,v.w));
  __shared__ float red[256];
  red[tid] = mx; __syncthreads();
  for (int st=128; st>0; st>>=1){
    if (tid<st) red[tid] = fmaxf(red[tid], red[tid+st]);
    __syncthreads();
  }
  float m = red[0]; __syncthreads();
  float4 e;
  e.x = expf(v.x-m); e.y = expf(v.y-m); e.z = expf(v.z-m); e.w = expf(v.w-m);
  red[tid] = e.x+e.y+e.z+e.w; __syncthreads();
  for (int st=128; st>0; st>>=1){
    if (tid<st) red[tid] += red[tid+st];
    __syncthreads();
  }
  float inv = 1.0f/red[0];
  e.x*=inv; e.y*=inv; e.z*=inv; e.w*=inv;
  *reinterpret_cast<float4*>(attn + bt*1024 + tid*4) = e;
}

// ---------------- part_sga[bt][sl][c] = sum_{n in slice} attn[n]*(scl[n][c]+pe[n][c]) ---
__launch_bounds__(256)
__global__ void sga2_k(const float* __restrict__ scl, const float* __restrict__ peN,
                       const float* __restrict__ attn, float* __restrict__ part){
  int bt = blockIdx.x, sl = blockIdx.y;   // 24 x 8
  int tid = threadIdx.x;
  __shared__ float at[128];
  if (tid < 128) at[tid] = attn[bt*1024 + sl*128 + tid];
  __syncthreads();
  float acc0 = 0.f, acc1 = 0.f;
  for (int j=0;j<128;j++){
    int n = sl*128 + j;
    float a = at[j];
    const float* row = scl + ((size_t)bt*1024 + n)*512;
    const float* pe  = peN + (size_t)n*512;
    acc0 += a * (row[tid] + pe[tid]);
    acc1 += a * (row[tid+256] + pe[tid+256]);
  }
  part[((size_t)bt*8 + sl)*512 + tid] = acc0;
  part[((size_t)bt*8 + sl)*512 + tid + 256] = acc1;
}

__global__ void sga_red(const float* __restrict__ part, float* __restrict__ sga){
  int bt = blockIdx.x; int tid = threadIdx.x;
  #pragma unroll
  for (int h=0; h<2; ++h){
    int c = tid + h*256;
    float s = 0.f;
    #pragma unroll
    for (int sl=0; sl<8; ++sl) s += part[((size_t)bt*8 + sl)*512 + c];
    sga[(size_t)bt*512 + c] = s;
  }
}

// ---------------- 512->512(relu)->128 MLP head (fp32 weights) ---------------------------
__launch_bounds__(256)
__global__ void mlp_k(const float* __restrict__ in, const float* __restrict__ w1,
                      const float* __restrict__ b1, const float* __restrict__ w2,
                      const float* __restrict__ b2, float* __restrict__ out){
  int bb = blockIdx.x; int tid = threadIdx.x;
  __shared__ float xv[512]; __shared__ float h[512];
  xv[tid] = in[(size_t)bb*512 + tid];
  xv[tid+256] = in[(size_t)bb*512 + 256 + tid];
  __syncthreads();
  #pragma unroll
  for (int oo=0;oo<2;oo++){
    int o = tid + oo*256;
    const float* wr = w1 + (size_t)o*512;
    float a=0.f;
    for (int c=0;c<512;c+=4){
      float4 q = *reinterpret_cast<const float4*>(wr+c);
      a += xv[c]*q.x + xv[c+1]*q.y + xv[c+2]*q.z + xv[c+3]*q.w;
    }
    h[o] = fmaxf(a + b1[o], 0.f);
  }
  __syncthreads();
  if (tid < 128){
    const float* wr = w2 + (size_t)tid*512;
    float a=0.f;
    for (int c=0;c<512;c+=4){
      float4 q = *reinterpret_cast<const float4*>(wr+c);
      a += h[c]*q.x + h[c+1]*q.y + h[c+2]*q.z + h[c+3]*q.w;
    }
    out[(size_t)bb*128+tid] = a + b2[tid];
  }
}

extern "C" void kernel_launch(void* const* d_in, const int* in_sizes, int n_in,
                              void* d_out, int out_size, void* d_ws, size_t ws_size,
                              hipStream_t stream){
  (void)in_sizes; (void)n_in; (void)out_size; (void)ws_size;
  const float* ctx   = (const float*)d_in[0];
  const float* frame = (const float*)d_in[1];
  const float* nl_vw[2] = {(const float*)d_in[4],  (const float*)d_in[11]};
  const float* nl_ow[2] = {(const float*)d_in[5],  (const float*)d_in[12]};
  const float* nl_ob[2] = {(const float*)d_in[6],  (const float*)d_in[13]};
  const float* nl_g[2]  = {(const float*)d_in[7],  (const float*)d_in[14]};
  const float* nl_be[2] = {(const float*)d_in[8],  (const float*)d_in[15]};
  const float* tp_w = (const float*)d_in[16]; const float* tp_b = (const float*)d_in[17];
  const float* up1w = (const float*)d_in[18]; const float* up1b = (const float*)d_in[19];
  const float* up2w = (const float*)d_in[20]; const float* up2b = (const float*)d_in[21];
  const float* og1w = (const float*)d_in[22]; const float* og1b = (const float*)d_in[23];
  const float* og2w = (const float*)d_in[24]; const float* og2b = (const float*)d_in[25];
  const float* os1w = (const float*)d_in[26]; const float* os1b = (const float*)d_in[27];
  const float* os2w = (const float*)d_in[28]; const float* os2b = (const float*)d_in[29];
  float* out = (float*)d_out;

  char* wsp = (char*)d_ws;
  // ---- persistent region (~23.9 MB) ----
  float* part_bn = (float*)(wsp);                 // 131072  [16][2048]
  float* mv      = (float*)(wsp + 131072);        // 8192
  float* gp      = (float*)(wsp + 139264);        // 8192
  float* SG      = (float*)(wsp + 147456);        // 98304
  float* attn    = (float*)(wsp + 245760);        // 98304
  float* sga     = (float*)(wsp + 344064);        // 49152
  float* psga    = (float*)(wsp + 393216);        // 393216 [24][8][512]
  float* peN     = (float*)(wsp + 786432);        // 2097152 [1024][512]
  bf16*  weff    = (bf16*) (wsp + 2883584);       // 2097152 [1024][1024] bf16
  unsigned short* w1sp = (unsigned short*)(wsp + 4980736);   // 12582912 [4][512][3072]
  unsigned short* w2sp = (unsigned short*)(wsp + 17563648);  // 6291456  [4][512][1536]
  char* ov = wsp + 23855104;
  // phase 1 (nonlocal):
  bf16*  xcl  = (bf16*) (ov);                     // 8 MB [4096][1024]
  float* ybuf = (float*)(ov + 8388608);           // 16 MB [4096][1024]
  // phase 2 (conv): wtt aliases ybuf (written after last norm2)
  unsigned short* wtt = (unsigned short*)(ov + 8388608);   // 28.3 MB [512][27648]
  float* part9 = (float*)(ov + 36700160);         // 28.9 MB [9][1568][512]
  // frame staging: aliases part9 (written after gp2_k reads part9)
  unsigned short* Fsp = (unsigned short*)(ov + 36700160);  // 9.4 MB [1536][3072]
  // phase 3 (after gp2_k; xcl/wtt dead):
  unsigned short* s1sp = (unsigned short*)(ov);   // 18.9 MB [6144][1536]
  float* scl  = (float*)(ov + 18874368);          // 50.3 MB [24576][512]

  // prep (independent)
  permT_k<bf16><<<dim3(4,16,16),256,0,stream>>>(ctx, xcl, 256, 1024, 1, 1, 262144L, 262144L);
  permTsplit3_k<1><<<dim3(32,16,1),256,0,stream>>>(up1w, w1sp, 2048, 1024, 4, 512, 0L, 0L);
  permTsplit3_k<1><<<dim3(32,8,1),256,0,stream>>>(up2w, w2sp, 2048, 512, 4, 512, 0L, 0L);
  pen_k<<<2048,256,0,stream>>>(peN);

  // nonlocal layers
  for (int l=0;l<2;l++){
    gemm_k<4><<<dim3(16,16),256,0,stream>>>(nl_ow[l], nl_vw[l], weff, 1024,1024,512);
    mmL_k<4,0><<<dim3(64,8,1),256,0,stream>>>((const unsigned short*)xcl,
        (const unsigned short*)weff, nl_ob[l], (const unsigned short*)xcl,
        ybuf, nullptr, 1024);
    stats2_k<<<dim3(8,16),256,0,stream>>>(ybuf, part_bn);
    stats_comb<<<4,256,0,stream>>>(part_bn, nl_g[l], nl_be[l], mv);
    norm2_k<<<16384,256,0,stream>>>(ybuf, mv, (unsigned short*)xcl);
  }

  // temporal-pool conv (im2col GEMM, K-split 9)
  wperm_k<<<512,256,0,stream>>>(tp_w, wtt);
  mmL_k<4,1><<<dim3(25,4,9),256,0,stream>>>((const unsigned short*)xcl, wtt,
      nullptr, nullptr, part9, nullptr, 3072);
  gp2_k<<<dim3(4,16),256,0,stream>>>(part9, tp_b, gp);

  // frame path (3-block split-bf16 == fp32-accurate); Fsp aliases part9 -> after gp2_k
  permTsplit3_k<0><<<dim3(1,16,24),256,0,stream>>>(frame, Fsp, 64, 1024, 1, 1, 65536L, 196608L);
  mmL_k<2,2><<<dim3(48,4,4),256,0,stream>>>(Fsp, w1sp, up1b, nullptr,
      nullptr, s1sp, 3072);
  mmL_k<4,3><<<dim3(96,4,4),256,0,stream>>>(s1sp, w2sp, up2b, nullptr,
      scl, nullptr, 1536);

  // attention tail
  sg2_k<<<dim3(24,16),256,0,stream>>>(scl, gp, SG);
  softmax_k<<<24,256,0,stream>>>(SG, attn);
  sga2_k<<<dim3(24,8),256,0,stream>>>(scl, peN, attn, psga);
  sga_red<<<24,256,0,stream>>>(psga, sga);

  // heads
  mlp_k<<<4,256,0,stream>>>(gp, og1w, og1b, og2w, og2b, out);
  mlp_k<<<24,256,0,stream>>>(sga, os1w, os1b, os2w, os2b, out + 512);
}